// Round 9
// baseline (78.245 us; speedup 1.0000x reference)
//
#include <hip/hip_runtime.h>
#include <hip/hip_bf16.h>
#include <math.h>

#define B_ 64
#define P_ 128
#define C_ 72
#define PADC 80    // f16 global row stride for A/Bc
#define BCS 88     // LDS row stride in halfs (176B -> 2-way banks, free)
#define IT 8       // i-rows per edge block

typedef __attribute__((ext_vector_type(8))) _Float16 half8v;
typedef __attribute__((ext_vector_type(2))) _Float16 half2v;
typedef __attribute__((ext_vector_type(4))) float f32x4;
typedef __attribute__((ext_vector_type(2))) float f32x2;
typedef __attribute__((ext_vector_type(4))) unsigned int u32x4;

// precomputed weight-fragment table (units: half8v, 64 per fragment)
#define FRAG_WE2  0          // We2 (+be2 @k=72), 15 frags
#define FRAG_WE1A (15 * 64)  // We1 rows 0..71, 15 frags
#define FRAG_WE1B (30 * 64)  // We1 rows 72..143 (+be1 @k=72), 15 frags
#define FRAG_WH1  (45 * 64)  // Wh1 (+bh1 @k=144), 25 frags
#define FRAG_WH2  (70 * 64)  // Wh2 (+bh2 @k=72), 15 frags
#define NFRAG 85

__device__ __forceinline__ float psi_f(float v) {
    float a = fabsf(v);
    return copysignf(__logf(1.0f + a), v);
}
template <int CTRL>
__device__ __forceinline__ float dpp_add(float v) {
    int s = __builtin_amdgcn_update_dpp(0, __builtin_bit_cast(int, v), CTRL, 0xF, 0xF, true);
    return v + __builtin_bit_cast(float, s);
}
// full sum across each 16-lane group (fixed tree -> deterministic)
__device__ __forceinline__ float red16(float v) {
    v = dpp_add<0xB1>(v);    // quad_perm(1,0,3,2)
    v = dpp_add<0x4E>(v);    // quad_perm(2,3,0,1)
    v = dpp_add<0x141>(v);   // row_half_mirror
    v = dpp_add<0x140>(v);   // row_mirror
    return v;
}
__device__ __forceinline__ half8v cvt8(const float* p) {
    f32x4 a = *(const f32x4*)p;
    f32x4 b = *(const f32x4*)(p + 4);
    half8v r = {(_Float16)a[0], (_Float16)a[1], (_Float16)a[2], (_Float16)a[3],
                (_Float16)b[0], (_Float16)b[1], (_Float16)b[2], (_Float16)b[3]};
    return r;
}

// ---------------- Kernel 0: build all weight fragments ------------------
__global__ __launch_bounds__(64) void setup_kernel(
    const float* __restrict__ We1, const float* __restrict__ be1,
    const float* __restrict__ We2, const float* __restrict__ be2,
    const float* __restrict__ Wh1, const float* __restrict__ bh1,
    const float* __restrict__ Wh2, const float* __restrict__ bh2,
    half8v* __restrict__ frags)
{
    const int bid = blockIdx.x;
    const int l = threadIdx.x;
    const int c16 = l & 15, g = l >> 4;

    const float* W;
    const float* bias;
    int kmax, rel;
    if (bid < 15)      { W = We2;            bias = be2;     kmax = 72;  rel = bid; }
    else if (bid < 30) { W = We1;            bias = nullptr; kmax = 72;  rel = bid - 15; }
    else if (bid < 45) { W = We1 + 72 * C_;  bias = be1;     kmax = 72;  rel = bid - 30; }
    else if (bid < 70) { W = Wh1;            bias = bh1;     kmax = 144; rel = bid - 45; }
    else               { W = Wh2;            bias = bh2;     kmax = 72;  rel = bid - 70; }
    const int kt = rel / 5, nt = rel - 5 * kt;
    const int n = nt * 16 + c16;

    half8v f = {};
    if (n < C_) {
        #pragma unroll
        for (int jj = 0; jj < 8; ++jj) {
            int k = kt * 32 + g * 8 + jj;
            float w = 0.f;
            if (k < kmax) w = W[k * C_ + n];
            else if (k == kmax && bias) w = bias[n];
            f[jj] = (_Float16)w;
        }
    }
    frags[bid * 64 + l] = f;
}

// ---------------- Kernel 1: pre (MFMA, sel split across grid) -----------
__global__ __launch_bounds__(64) void pre_kernel(
    const float* __restrict__ h, const half8v* __restrict__ frags,
    _Float16* __restrict__ Ah, _Float16* __restrict__ Bch)
{
    const int l = threadIdx.x, c16 = l & 15, g = l >> 4;
    const int sel = blockIdx.x & 1;
    const int m0 = (blockIdx.x >> 1) * 16;

    const float* hrow = h + (m0 + c16) * C_;
    half8v a0 = cvt8(hrow + g * 8);
    half8v a1 = cvt8(hrow + 32 + g * 8);
    half8v a2 = {};
    if (g == 0) a2 = cvt8(hrow + 64);
    else if (g == 1) a2[0] = (_Float16)1.0f;   // bias row k=72

    const half8v* F = frags + (sel ? FRAG_WE1B : FRAG_WE1A);
    f32x4 acc[5] = {};
    #pragma unroll
    for (int kt = 0; kt < 3; ++kt) {
        half8v a = (kt == 0) ? a0 : (kt == 1 ? a1 : a2);
        #pragma unroll
        for (int nt = 0; nt < 5; ++nt)
            acc[nt] = __builtin_amdgcn_mfma_f32_16x16x32_f16(a, F[(kt * 5 + nt) * 64 + l], acc[nt], 0, 0, 0);
    }
    _Float16* dst = sel ? Bch : Ah;
    #pragma unroll
    for (int nt = 0; nt < 5; ++nt) {
        int n = nt * 16 + c16;
        if (n < C_) {
            #pragma unroll
            for (int r = 0; r < 4; ++r)
                dst[(m0 + 4 * g + r) * PADC + n] = (_Float16)acc[nt][r];
        }
    }
}

// ---------------- Kernel 2: edge MLP, jt-outer / ii-inner (2-way ILP) ---
__global__ __launch_bounds__(256) void edge_kernel(
    const float* __restrict__ x, const _Float16* __restrict__ Ah,
    const _Float16* __restrict__ Bch, const float* __restrict__ We1,
    const half8v* __restrict__ frags,
    const float* __restrict__ Wm, const float* __restrict__ bm,
    const float* __restrict__ Wx,
    float* __restrict__ wm_out, float* __restrict__ xacc_out)
{
    __shared__ __align__(16) _Float16 A_s[IT][PADC];
    __shared__ __align__(16) _Float16 Bc_s[P_][BCS];
    __shared__ __align__(16) float xj_s[P_][4];

    const int b  = blockIdx.x >> 4;
    const int it = blockIdx.x & 15;
    const int t  = threadIdx.x;
    const int wv = t >> 6;
    const int l  = t & 63;
    const int c16 = l & 15;
    const int g   = l >> 4;

    // ---- stage to LDS (A, Bc, xj only) ----
    {
        const unsigned int* Asrc = (const unsigned int*)(Ah + (b * P_ + it * IT) * PADC);
        for (int idx = t; idx < IT * PADC / 2; idx += 256)
            ((unsigned int*)A_s)[idx] = Asrc[idx];
        for (int cidx = t; cidx < P_ * 10; cidx += 256) {
            int r = cidx / 10, c = cidx - r * 10;
            *(u32x4*)&Bc_s[r][c * 8] = ((const u32x4*)(Bch + (b * P_ + r) * PADC))[c];
        }
        for (int idx = t; idx < P_ * 4; idx += 256)
            ((float*)xj_s)[idx] = x[b * P_ * 4 + idx];
    }

    // ---- wave-lifetime register constants (no LDS) ----
    const float* w1g = We1 + 144 * C_;
    const float* w2g = We1 + 145 * C_;
    half8v w1a = cvt8(w1g + g * 8);
    half8v w1b = cvt8(w1g + 32 + g * 8);
    half8v w1c = cvt8(w1g + 64);
    half8v w2a = cvt8(w2g + g * 8);
    half8v w2b = cvt8(w2g + 32 + g * 8);
    half8v w2c = cvt8(w2g + 64);

    half8v Wf[3][5];
    #pragma unroll
    for (int kt = 0; kt < 3; ++kt)
        #pragma unroll
        for (int nt = 0; nt < 5; ++nt)
            Wf[kt][nt] = frags[FRAG_WE2 + (kt * 5 + nt) * 64 + l];

    // per-lane channel weights (ch = nt*16 + 4g + r), f32 pair {Wm, Wx}
    f32x2 WmWx[5][4];
    #pragma unroll
    for (int nt = 0; nt < 5; ++nt)
        #pragma unroll
        for (int r = 0; r < 4; ++r) {
            int ch = nt * 16 + 4 * g + r;
            bool ok = ch < C_;
            WmWx[nt][r][0] = ok ? Wm[ch] : 0.f;
            WmWx[nt][r][1] = ok ? Wx[ch] : 0.f;
        }
    const float bm0 = bm[0];
    const f32x4 zero4 = {0.f, 0.f, 0.f, 0.f};

    __syncthreads();

    const int i0 = it * IT + wv * 2;       // this wave's two i-rows
    const int node0 = b * P_ + i0;
    const f32x4 xiA = *(const f32x4*)&xj_s[i0][0];
    const f32x4 xiB = *(const f32x4*)&xj_s[i0 + 1][0];

    // A-row chunks for both i's, constant across the jt loop
    half8v avA0 = *(const half8v*)&A_s[wv * 2][g * 8];
    half8v avA1 = *(const half8v*)&A_s[wv * 2][32 + g * 8];
    half8v avA2 = *(const half8v*)&A_s[wv * 2][64];
    half8v avB0 = *(const half8v*)&A_s[wv * 2 + 1][g * 8];
    half8v avB1 = *(const half8v*)&A_s[wv * 2 + 1][32 + g * 8];
    half8v avB2 = *(const half8v*)&A_s[wv * 2 + 1][64];

    f32x4 wmaccA[5] = {}, wmaccB[5] = {};
    f32x4 xaccA = {0.f, 0.f, 0.f, 0.f}, xaccB = {0.f, 0.f, 0.f, 0.f};

    #pragma unroll 1
    for (int jt = 0; jt < 8; ++jt) {
        const int j = jt * 16 + c16;
        const f32x4 xjv = *(const f32x4*)&xj_s[j][0];
        // shared Bc chunks (one set of ds_reads for both chains)
        half8v bc0 = *(const half8v*)&Bc_s[j][g * 8];
        half8v bc1 = *(const half8v*)&Bc_s[j][32 + g * 8];
        half8v bc2 = *(const half8v*)&Bc_s[j][64];
        half8v zero8 = {};

        // ---------- chain A (i = i0) ----------
        float dA0 = xiA[0] - xjv[0], dA1 = xiA[1] - xjv[1];
        float dA2 = xiA[2] - xjv[2], dA3 = xiA[3] - xjv[3];
        float nnA = dA0 * dA0 - dA1 * dA1 - dA2 * dA2 - dA3 * dA3;
        float ppA = xiA[0] * xjv[0] - xiA[1] * xjv[1] - xiA[2] * xjv[2] - xiA[3] * xjv[3];
        _Float16 nhA = (_Float16)psi_f(nnA);
        _Float16 phA = (_Float16)psi_f(ppA);
        half8v n8A = {nhA, nhA, nhA, nhA, nhA, nhA, nhA, nhA};
        half8v p8A = {phA, phA, phA, phA, phA, phA, phA, phA};

        // ---------- chain B (i = i0+1) ----------
        float dB0 = xiB[0] - xjv[0], dB1 = xiB[1] - xjv[1];
        float dB2 = xiB[2] - xjv[2], dB3 = xiB[3] - xjv[3];
        float nnB = dB0 * dB0 - dB1 * dB1 - dB2 * dB2 - dB3 * dB3;
        float ppB = xiB[0] * xjv[0] - xiB[1] * xjv[1] - xiB[2] * xjv[2] - xiB[3] * xjv[3];
        _Float16 nhB = (_Float16)psi_f(nnB);
        _Float16 phB = (_Float16)psi_f(ppB);
        half8v n8B = {nhB, nhB, nhB, nhB, nhB, nhB, nhB, nhB};
        half8v p8B = {phB, phB, phB, phB, phB, phB, phB, phB};

        auto mk = [&](half8v av, half8v bv, half8v w1, half8v w2,
                      half8v n8, half8v p8) -> half8v {
            half8v v = av + bv;
            v = __builtin_elementwise_fma(w1, n8, v);
            v = __builtin_elementwise_fma(w2, p8, v);
            return __builtin_elementwise_max(v, zero8);
        };
        half8v afA0 = mk(avA0, bc0, w1a, w2a, n8A, p8A);
        half8v afA1 = mk(avA1, bc1, w1b, w2b, n8A, p8A);
        half8v afB0 = mk(avB0, bc0, w1a, w2a, n8B, p8B);
        half8v afB1 = mk(avB1, bc1, w1b, w2b, n8B, p8B);
        half8v afA2 = {}, afB2 = {};
        if (g == 0) {
            afA2 = mk(avA2, bc2, w1c, w2c, n8A, p8A);
            afB2 = mk(avB2, bc2, w1c, w2c, n8B, p8B);
        } else if (g == 1) {
            afA2[0] = (_Float16)1.0f;   // be2 bias row k=72
            afB2[0] = (_Float16)1.0f;
        }

        // ---------- MFMAs: two independent 15-chains ----------
        f32x4 accA[5] = {}, accB[5] = {};
        #pragma unroll
        for (int nt = 0; nt < 5; ++nt) {
            accA[nt] = __builtin_amdgcn_mfma_f32_16x16x32_f16(Wf[0][nt], afA0, accA[nt], 0, 0, 0);
            accB[nt] = __builtin_amdgcn_mfma_f32_16x16x32_f16(Wf[0][nt], afB0, accB[nt], 0, 0, 0);
        }
        #pragma unroll
        for (int nt = 0; nt < 5; ++nt) {
            accA[nt] = __builtin_amdgcn_mfma_f32_16x16x32_f16(Wf[1][nt], afA1, accA[nt], 0, 0, 0);
            accB[nt] = __builtin_amdgcn_mfma_f32_16x16x32_f16(Wf[1][nt], afB1, accB[nt], 0, 0, 0);
        }
        #pragma unroll
        for (int nt = 0; nt < 5; ++nt) {
            accA[nt] = __builtin_amdgcn_mfma_f32_16x16x32_f16(Wf[2][nt], afA2, accA[nt], 0, 0, 0);
            accB[nt] = __builtin_amdgcn_mfma_f32_16x16x32_f16(Wf[2][nt], afB2, accB[nt], 0, 0, 0);
        }

        // ---------- phase C, both chains (f32x2 pk-fma dots) ----------
        f32x2 wdpdA = {0.f, 0.f}, wdpdB = {0.f, 0.f};
        #pragma unroll
        for (int nt = 0; nt < 5; ++nt) {
            f32x4 mA = __builtin_elementwise_max(accA[nt], zero4);
            f32x4 mB = __builtin_elementwise_max(accB[nt], zero4);
            accA[nt] = mA;
            accB[nt] = mB;
            #pragma unroll
            for (int r = 0; r < 4; ++r) {
                f32x2 vA = {mA[r], mA[r]};
                f32x2 vB = {mB[r], mB[r]};
                wdpdA = __builtin_elementwise_fma(vA, WmWx[nt][r], wdpdA);
                wdpdB = __builtin_elementwise_fma(vB, WmWx[nt][r], wdpdB);
            }
        }
        // reduce across the 4 g-groups (lanes xor 16, 32), chains interleaved
        {
            f32x2 sA, sB;
            sA[0] = __shfl_xor(wdpdA[0], 16, 64);
            sB[0] = __shfl_xor(wdpdB[0], 16, 64);
            sA[1] = __shfl_xor(wdpdA[1], 16, 64);
            sB[1] = __shfl_xor(wdpdB[1], 16, 64);
            wdpdA += sA; wdpdB += sB;
            sA[0] = __shfl_xor(wdpdA[0], 32, 64);
            sB[0] = __shfl_xor(wdpdB[0], 32, 64);
            sA[1] = __shfl_xor(wdpdA[1], 32, 64);
            sB[1] = __shfl_xor(wdpdB[1], 32, 64);
            wdpdA += sA; wdpdB += sB;
        }
        float wA = __builtin_amdgcn_rcpf(1.f + __expf(-(wdpdA[0] + bm0)));
        float wB = __builtin_amdgcn_rcpf(1.f + __expf(-(wdpdB[0] + bm0)));
        f32x4 w4A = {wA, wA, wA, wA};
        f32x4 w4B = {wB, wB, wB, wB};
        #pragma unroll
        for (int nt = 0; nt < 5; ++nt) {
            wmaccA[nt] = __builtin_elementwise_fma(w4A, accA[nt], wmaccA[nt]);
            wmaccB[nt] = __builtin_elementwise_fma(w4B, accB[nt], wmaccB[nt]);
        }
        f32x4 pdA = {wdpdA[1], wdpdA[1], wdpdA[1], wdpdA[1]};
        f32x4 pdB = {wdpdB[1], wdpdB[1], wdpdB[1], wdpdB[1]};
        xaccA = __builtin_elementwise_fma(pdA, xjv, xaccA);
        xaccB = __builtin_elementwise_fma(pdB, xjv, xaccB);
    } // jt

    // ---- finalize: sum across the 16 edge-lanes of each row ----
    #pragma unroll
    for (int nt = 0; nt < 5; ++nt)
        #pragma unroll
        for (int r = 0; r < 4; ++r) {
            wmaccA[nt][r] = red16(wmaccA[nt][r]);
            wmaccB[nt][r] = red16(wmaccB[nt][r]);
        }
    #pragma unroll
    for (int q = 0; q < 4; ++q) {
        xaccA[q] = red16(xaccA[q]);
        xaccB[q] = red16(xaccB[q]);
    }

    if (c16 == 0) {
        #pragma unroll
        for (int nt = 0; nt < 5; ++nt)
            #pragma unroll
            for (int r = 0; r < 4; ++r) {
                int ch = nt * 16 + 4 * g + r;
                if (ch < C_) {
                    wm_out[node0 * C_ + ch] = wmaccA[nt][r];
                    wm_out[(node0 + 1) * C_ + ch] = wmaccB[nt][r];
                }
            }
    }
    if (l == 0) {
        *(f32x4*)&xacc_out[node0 * 4] = xaccA;
        *(f32x4*)&xacc_out[(node0 + 1) * 4] = xaccB;
    }
}

// ---------------- Kernel 3: node MLP (chained MFMAs, frag loads) --------
__global__ __launch_bounds__(64) void node_kernel(
    const float* __restrict__ x, const float* __restrict__ h,
    const half8v* __restrict__ frags,
    const float* __restrict__ wm, const float* __restrict__ xacc,
    float* __restrict__ hout, float* __restrict__ xout)
{
    __shared__ _Float16 g_s[16][BCS];
    const int l = threadIdx.x, c16 = l & 15, g = l >> 4;
    const int m0 = blockIdx.x * 16;

    const float* hrow  = h  + (m0 + c16) * C_;
    const float* wmrow = wm + (m0 + c16) * C_;

    // ---- GEMM1: [h|wm|1] (K=160) @ Wh1(+bh1 row 144) ----
    half8v a[5];
    #pragma unroll
    for (int kt = 0; kt < 5; ++kt) {
        int k = kt * 32 + g * 8;
        half8v v = {};
        if (k < C_) v = cvt8(hrow + k);
        else if (k < 144) v = cvt8(wmrow + (k - C_));
        else if (k == 144) v[0] = (_Float16)1.0f;
        a[kt] = v;
    }
    f32x4 acc1[5] = {};
    #pragma unroll
    for (int kt = 0; kt < 5; ++kt)
        #pragma unroll
        for (int nt = 0; nt < 5; ++nt)
            acc1[nt] = __builtin_amdgcn_mfma_f32_16x16x32_f16(
                a[kt], frags[FRAG_WH1 + (kt * 5 + nt) * 64 + l], acc1[nt], 0, 0, 0);

    // relu -> wave-local LDS transpose (D layout -> A-fragment layout)
    #pragma unroll
    for (int nt = 0; nt < 5; ++nt) {
        int n = nt * 16 + c16;
        #pragma unroll
        for (int r = 0; r < 4; ++r)
            g_s[4 * g + r][n] = (_Float16)fmaxf(acc1[nt][r], 0.f);
    }
    half8v b0 = *(const half8v*)&g_s[c16][g * 8];
    half8v b1 = *(const half8v*)&g_s[c16][32 + g * 8];
    half8v b2 = {};
    if (g == 0) b2 = *(const half8v*)&g_s[c16][64];
    else if (g == 1) b2[0] = (_Float16)1.0f;   // bh2 bias row k=72

    // ---- GEMM2: g (K=96) @ Wh2(+bh2 row 72) ----
    f32x4 acc2[5] = {};
    #pragma unroll
    for (int kt = 0; kt < 3; ++kt) {
        half8v aa = (kt == 0) ? b0 : (kt == 1 ? b1 : b2);
        #pragma unroll
        for (int nt = 0; nt < 5; ++nt)
            acc2[nt] = __builtin_amdgcn_mfma_f32_16x16x32_f16(
                aa, frags[FRAG_WH2 + (kt * 5 + nt) * 64 + l], acc2[nt], 0, 0, 0);
    }
    #pragma unroll
    for (int nt = 0; nt < 5; ++nt) {
        int n = nt * 16 + c16;
        if (n < C_) {
            #pragma unroll
            for (int r = 0; r < 4; ++r) {
                int row = m0 + 4 * g + r;
                hout[row * C_ + n] = h[row * C_ + n] + acc2[nt][r];
            }
        }
    }
    {
        int row = m0 + (l >> 2), d = l & 3;
        xout[row * 4 + d] = x[row * 4 + d] + 0.005f * (xacc[row * 4 + d] * (1.0f / 128.f));
    }
}

extern "C" void kernel_launch(void* const* d_in, const int* in_sizes, int n_in,
                              void* d_out, int out_size, void* d_ws, size_t ws_size,
                              hipStream_t stream) {
    const float* x   = (const float*)d_in[0];
    const float* h   = (const float*)d_in[1];
    const float* We1 = (const float*)d_in[2];
    const float* be1 = (const float*)d_in[3];
    const float* We2 = (const float*)d_in[4];
    const float* be2 = (const float*)d_in[5];
    const float* Wm  = (const float*)d_in[6];
    const float* bm  = (const float*)d_in[7];
    const float* Wh1 = (const float*)d_in[8];
    const float* bh1 = (const float*)d_in[9];
    const float* Wh2 = (const float*)d_in[10];
    const float* bh2 = (const float*)d_in[11];
    const float* Wx  = (const float*)d_in[12];

    const int NNODE = B_ * P_;                       // 8192
    _Float16* Ah  = (_Float16*)d_ws;                 // [8192][80] f16
    _Float16* Bch = Ah + NNODE * PADC;               // [8192][80] f16
    float* wm   = (float*)(Bch + NNODE * PADC);      // [8192][72] f32
    float* xacc = wm + NNODE * C_;                   // [8192][4]  f32
    half8v* frags = (half8v*)(xacc + NNODE * 4);     // 85 frags x 1KB

    float* hout = (float*)d_out;                     // [8192][72]
    float* xout = hout + NNODE * C_;                 // [8192][4]

    setup_kernel<<<NFRAG, 64, 0, stream>>>(We1, be1, We2, be2, Wh1, bh1, Wh2, bh2, frags);
    pre_kernel<<<NNODE / 16 * 2, 64, 0, stream>>>(h, frags, Ah, Bch);
    edge_kernel<<<B_ * 16, 256, 0, stream>>>(x, Ah, Bch, We1, frags,
                                             Wm, bm, Wx, wm, xacc);
    node_kernel<<<NNODE / 16, 64, 0, stream>>>(x, h, frags, wm, xacc, hout, xout);
}